// Round 6
// baseline (874.289 us; speedup 1.0000x reference)
//
#include <hip/hip_runtime.h>
#include <cmath>
#include <cfloat>

#define DEV __device__ __forceinline__

DEV unsigned enc_f(float x) { unsigned u = __float_as_uint(x); return (u >> 31) ? ~u : (u | 0x80000000u); }
DEV float dec_f(unsigned u) { return __uint_as_float((u >> 31) ? (u & 0x7FFFFFFFu) : ~u); }

// ---------------- XCD-partitioned degree count + rank capture (+ encoder in last block) -------
// rank[i] = # of earlier-processed edges with the same dst -> scatter needs no atomics.
__global__ __launch_bounds__(256) void enc_count_kernel(
    const int* __restrict__ dst, int* __restrict__ deg, int* __restrict__ rank,
    int E, int N, int nCount,
    const int* __restrict__ ids, const float* __restrict__ rssi,
    const float* __restrict__ emb, const float* __restrict__ ew, const float* __restrict__ eb,
    const float* __restrict__ Wl0, const float* __restrict__ Wr0, const float* __restrict__ b0,
    float* __restrict__ zout, int NQ)
{
    if (blockIdx.x < (unsigned)nCount) {
        const int part = blockIdx.x & 7;
        const int chunk = blockIdx.x >> 3;
        const int npart = (N + 7) >> 3;
        const int lo = part * npart;
        const int hi = min(lo + npart, N);
        const int base = chunk * 4096 + threadIdx.x;
#pragma unroll
        for (int it = 0; it < 16; ++it) {
            int i = base + it * 256;
            if (i < E) {
                int d = dst[i];
                if (d >= lo && d < hi) rank[i] = atomicAdd(&deg[d], 1);
            }
        }
        return;
    }
    __shared__ float zsh[4][64];
    __shared__ float zq[64];
    int j = threadIdx.x & 63;
    int g = threadIdx.x >> 6;
    float acc = 0.f;
    for (int q = g; q < NQ; q += 4) {
        int id = ids[q];
        const float* e = emb + (size_t)id * 32;
        float p = eb[j];
#pragma unroll
        for (int k = 0; k < 32; ++k) p = fmaf(e[k], ew[k * 64 + j], p);
        p = fmaf(rssi[q], ew[32 * 64 + j], p);
        acc += fmaxf(p, 0.f);
    }
    zsh[g][j] = acc;
    __syncthreads();
    if (g == 0) {
        float z = (zsh[0][j] + zsh[1][j] + zsh[2][j] + zsh[3][j]) / (float)NQ;
        zq[j] = z;
        zout[j] = z;
    }
    __syncthreads();
    if (g == 0) {
        float cl = 0.f, cr = 0.f;
        for (int k = 0; k < 64; ++k) {
            float zk = zq[k];
            cl = fmaf(zk, Wl0[(128 + k) * 64 + j], cl);
            cr = fmaf(zk, Wr0[(128 + k) * 64 + j], cr);
        }
        zout[64 + j] = cl;
        zout[128 + j] = cr + b0[j];
    }
}

// ---------------- CSR build: scanA (local) + scanC (per-block prefix of bsum) ----------------
__global__ __launch_bounds__(256) void scanA_kernel(const int* __restrict__ deg, int* __restrict__ offs,
                                                    int* __restrict__ bsum, unsigned* __restrict__ red, int N)
{
    __shared__ int sh[256];
    int t = threadIdx.x;
    if (blockIdx.x == 0 && t < 8) red[t] = 0u;
    int i = blockIdx.x * 256 + t;
    int v = (i < N) ? deg[i] : 0;
    sh[t] = v;
    __syncthreads();
#pragma unroll
    for (int d = 1; d < 256; d <<= 1) {
        int u = (t >= d) ? sh[t - d] : 0;
        __syncthreads();
        sh[t] += u;
        __syncthreads();
    }
    if (i < N) offs[i] = sh[t] - v;
    if (t == 255) bsum[blockIdx.x] = sh[255];
}

// Each block recomputes its exclusive prefix over bsum (NB<=256 values) -> no scanB launch.
__global__ __launch_bounds__(256) void scanC_kernel(int* __restrict__ offs, const int* __restrict__ bsum,
                                                    int N, int NB)
{
    __shared__ int sh[256];
    int t = threadIdx.x;
    int bid = blockIdx.x;
    int s = 0;
    for (int j = t; j < bid; j += 256) s += bsum[j];
    sh[t] = s;
    __syncthreads();
#pragma unroll
    for (int d = 128; d >= 1; d >>= 1) {
        if (t < d) sh[t] += sh[t + d];
        __syncthreads();
    }
    int base = sh[0];
    int i = bid * 256 + t;
    if (i < N) offs[i] += base;
    if (bid == NB - 1 && t == 0) offs[N] = base + bsum[NB - 1];
}

// ---------------- combined: atomic-free scatter + layer-0 GEMM (independent work) ------------
__global__ __launch_bounds__(256) void scatter_gemm0_kernel(
    const int* __restrict__ src, const int* __restrict__ dst,
    const int* __restrict__ rank, const int* __restrict__ offs,
    int* __restrict__ srcs, int E, int N,
    const float* __restrict__ A, const float* __restrict__ B1, const float* __restrict__ B2,
    const float* __restrict__ add2, float* __restrict__ O1, float* __restrict__ O2, int nGemm)
{
    __shared__ float As[64][36];    // 9.2 KB
    __shared__ float Bs[32][128];   // 16.4 KB

    if (blockIdx.x >= (unsigned)nGemm) {
        const int chunk = blockIdx.x - nGemm;
        const int base = chunk * 4096 + threadIdx.x;
#pragma unroll
        for (int it = 0; it < 16; ++it) {
            int i = base + it * 256;
            if (i < E) {
                int d = dst[i];
                srcs[offs[d] + rank[i]] = src[i];
            }
        }
        return;
    }

    const int tid = threadIdx.x;
    const int cg = tid & 15;        // 16 col groups x 8 cols = 128
    const int rg = tid >> 4;        // 16 row groups x 4 rows = 64
    const int row0 = blockIdx.x * 64;

    float acc[4][8];
#pragma unroll
    for (int i = 0; i < 4; ++i)
#pragma unroll
        for (int j = 0; j < 8; ++j) acc[i][j] = 0.f;

    for (int kc = 0; kc < 128; kc += 32) {
#pragma unroll
        for (int i = 0; i < 2; ++i) {
            int vi = i * 256 + tid;
            int r = vi >> 3;
            int k4 = (vi & 7) << 2;
            int row = row0 + r;
            float4 v = make_float4(0.f, 0.f, 0.f, 0.f);
            if (row < N) v = *(const float4*)(A + (size_t)row * 128 + kc + k4);
            *(float4*)&As[r][k4] = v;
        }
#pragma unroll
        for (int i = 0; i < 4; ++i) {
            int vi = i * 256 + tid;
            int k = vi >> 5;
            int c = (vi & 31) << 2;
            const float* sp = (c < 64) ? (B1 + (size_t)(kc + k) * 64 + c)
                                       : (B2 + (size_t)(kc + k) * 64 + (c - 64));
            *(float4*)&Bs[k][c] = *(const float4*)sp;
        }
        __syncthreads();
#pragma unroll
        for (int k4 = 0; k4 < 32; k4 += 4) {
            float4 a4[4];
#pragma unroll
            for (int i = 0; i < 4; ++i)
                a4[i] = *(const float4*)&As[rg * 4 + i][k4];
#pragma unroll
            for (int j = 0; j < 4; ++j) {
                float4 b0v = *(const float4*)&Bs[k4 + j][cg * 8];
                float4 b1v = *(const float4*)&Bs[k4 + j][cg * 8 + 4];
#pragma unroll
                for (int i = 0; i < 4; ++i) {
                    float av = ((const float*)&a4[i])[j];
                    acc[i][0] = fmaf(av, b0v.x, acc[i][0]);
                    acc[i][1] = fmaf(av, b0v.y, acc[i][1]);
                    acc[i][2] = fmaf(av, b0v.z, acc[i][2]);
                    acc[i][3] = fmaf(av, b0v.w, acc[i][3]);
                    acc[i][4] = fmaf(av, b1v.x, acc[i][4]);
                    acc[i][5] = fmaf(av, b1v.y, acc[i][5]);
                    acc[i][6] = fmaf(av, b1v.z, acc[i][6]);
                    acc[i][7] = fmaf(av, b1v.w, acc[i][7]);
                }
            }
        }
        __syncthreads();
    }

    int c0 = cg * 8;
    float* O; int c; const float* addp = nullptr;
    if (c0 < 64) { O = O1; c = c0; }
    else         { O = O2; c = c0 - 64; addp = add2; }
    float4 av0 = make_float4(0.f, 0.f, 0.f, 0.f), av1 = av0;
    if (addp) { av0 = *(const float4*)(addp + c); av1 = *(const float4*)(addp + c + 4); }
#pragma unroll
    for (int i = 0; i < 4; ++i) {
        int row = row0 + rg * 4 + i;
        if (row < N) {
            float4 o0, o1;
            o0.x = acc[i][0] + av0.x; o0.y = acc[i][1] + av0.y;
            o0.z = acc[i][2] + av0.z; o0.w = acc[i][3] + av0.w;
            o1.x = acc[i][4] + av1.x; o1.y = acc[i][5] + av1.y;
            o1.z = acc[i][6] + av1.z; o1.w = acc[i][7] + av1.w;
            *(float4*)(O + (size_t)row * 64 + c) = o0;
            *(float4*)(O + (size_t)row * 64 + c + 4) = o1;
        }
    }
}

// ---------------- layer-0 aggregation (float4 16-lane gather, no LDS -> max occupancy) -------
__global__ __launch_bounds__(256) void agg_kernel(
    const float* __restrict__ m, const float* __restrict__ r,
    const int* __restrict__ off, const int* __restrict__ srcs,
    const float* __restrict__ cl, float* __restrict__ hout, int N)
{
    const int tid = threadIdx.x;
    const int lane = tid & 63;
    const int wave = tid >> 6;
    const int grp = lane >> 4;
    const int l16 = lane & 15;
    const int node0 = blockIdx.x * 64;

    int offv = off[min(node0 + lane, N)];
    int offend = off[min(node0 + 64, N)];
    float4 cl4 = *(const float4*)(cl + l16 * 4);

    int e0p = __shfl(offv, wave);
    int e1p = (wave < 63) ? __shfl(offv, wave + 1) : offend;
    int sv = (e0p + lane < e1p) ? srcs[e0p + lane] : 0;

    for (int idx = 0; idx < 16; ++idx) {
        int nn = wave + idx * 4;
        int node = node0 + nn;
        int e0 = __shfl(offv, nn);
        int e1 = (nn < 63) ? __shfl(offv, nn + 1) : offend;
        int cur_sv = sv;
        if (idx < 15) {
            int nx = nn + 4;
            int ne0 = __shfl(offv, nx);
            int ne1 = (nx < 63) ? __shfl(offv, nx + 1) : offend;
            sv = (ne0 + lane < ne1) ? srcs[ne0 + lane] : 0;
        }
        float4 r4 = make_float4(0.f, 0.f, 0.f, 0.f);
        if (node < N) r4 = *((const float4*)(r + (size_t)node * 64) + l16);

        float4 acc4[4];
#pragma unroll
        for (int t = 0; t < 4; ++t) acc4[t] = make_float4(0.f, 0.f, 0.f, 0.f);

        for (int base = e0; base < e1; base += 64) {
            int cnt = min(e1 - base, 64);
            int svs = (base == e0) ? cur_sv : ((base + lane < e1) ? srcs[base + lane] : 0);
            for (int u = 0; u < cnt; u += 16) {
#pragma unroll
                for (int t = 0; t < 4; ++t) {
                    int ei = u + t * 4 + grp;
                    int s = __shfl(svs, ei);
                    if (ei < cnt) {
                        float4 v = *((const float4*)(m + (size_t)s * 64) + l16);
                        acc4[t].x += v.x; acc4[t].y += v.y;
                        acc4[t].z += v.z; acc4[t].w += v.w;
                    }
                }
            }
        }
        float4 tot;
        tot.x = (acc4[0].x + acc4[1].x) + (acc4[2].x + acc4[3].x);
        tot.y = (acc4[0].y + acc4[1].y) + (acc4[2].y + acc4[3].y);
        tot.z = (acc4[0].z + acc4[1].z) + (acc4[2].z + acc4[3].z);
        tot.w = (acc4[0].w + acc4[1].w) + (acc4[2].w + acc4[3].w);
        tot.x += __shfl_xor(tot.x, 16); tot.x += __shfl_xor(tot.x, 32);
        tot.y += __shfl_xor(tot.y, 16); tot.y += __shfl_xor(tot.y, 32);
        tot.z += __shfl_xor(tot.z, 16); tot.z += __shfl_xor(tot.z, 32);
        tot.w += __shfl_xor(tot.w, 16); tot.w += __shfl_xor(tot.w, 32);

        int deg = e1 - e0;
        float inv = 1.f / (float)(deg > 0 ? deg : 1);
        if (lane < 16 && node < N) {
            float cadd = (deg > 0) ? 1.f : 0.f;
            float4 o;
            o.x = fmaxf(fmaf(tot.x, inv, fmaf(cadd, cl4.x, r4.x)), 0.f);
            o.y = fmaxf(fmaf(tot.y, inv, fmaf(cadd, cl4.y, r4.y)), 0.f);
            o.z = fmaxf(fmaf(tot.z, inv, fmaf(cadd, cl4.z, r4.z)), 0.f);
            o.w = fmaxf(fmaf(tot.w, inv, fmaf(cadd, cl4.w, r4.w)), 0.f);
            *(float4*)(hout + (size_t)node * 64 + l16 * 4) = o;
        }
    }
}

// ---------------- fused SAGE layer (layers 1-2): slim LDS (17KB), NO forced occupancy --------
// As holds ONLY the gathered mean (own-h read direct from global in phase 2: L1 broadcast).
// Bs staging kept (round-4 known-good). VGPR must stay <=64 naturally -> 8 blocks/CU.
template <bool SCORER>
__global__ __launch_bounds__(256) void sage_fused_kernel(
    const float* __restrict__ h,
    const int* __restrict__ off, const int* __restrict__ srcs,
    const float* __restrict__ Wl, const float* __restrict__ Wr, const float* __restrict__ bias,
    const float* __restrict__ sw1, const float* __restrict__ sb1,
    const float* __restrict__ sw2, const float* __restrict__ sb2,
    float* __restrict__ hout, float* __restrict__ sbuf, unsigned* __restrict__ red, int N)
{
    __shared__ float As[32][68];    // 8.7 KB: gathered mean per node (stride 68 -> bank spread)
    __shared__ float Bs[32][64];    // 8 KB weight chunk

    const int tid = threadIdx.x;
    const int lane = tid & 63;
    const int wave = tid >> 6;
    const int grp = lane >> 4;
    const int l16 = lane & 15;
    const int node0 = blockIdx.x * 32;

    int offv = off[min(node0 + lane, N)];   // lanes 0..32 used

    // ---- Phase 1: gather mean only (own-h NOT staged -> fewer regs than round 4)
    int e0p = __shfl(offv, wave);
    int e1p = __shfl(offv, wave + 1);
    int sv = (e0p + lane < e1p) ? srcs[e0p + lane] : 0;

    for (int idx = 0; idx < 8; ++idx) {
        int nn = wave + idx * 4;
        int e0 = __shfl(offv, nn);
        int e1 = __shfl(offv, nn + 1);
        int cur_sv = sv;
        if (idx < 7) {
            int nx = nn + 4;
            int ne0 = __shfl(offv, nx);
            int ne1 = __shfl(offv, nx + 1);
            sv = (ne0 + lane < ne1) ? srcs[ne0 + lane] : 0;
        }

        float4 acc4[4];
#pragma unroll
        for (int t = 0; t < 4; ++t) acc4[t] = make_float4(0.f, 0.f, 0.f, 0.f);

        for (int base = e0; base < e1; base += 64) {
            int cnt = min(e1 - base, 64);
            int svs = (base == e0) ? cur_sv : ((base + lane < e1) ? srcs[base + lane] : 0);
            for (int u = 0; u < cnt; u += 16) {
#pragma unroll
                for (int t = 0; t < 4; ++t) {
                    int ei = u + t * 4 + grp;
                    int s = __shfl(svs, ei);
                    if (ei < cnt) {
                        float4 v = *((const float4*)(h + (size_t)s * 64) + l16);
                        acc4[t].x += v.x; acc4[t].y += v.y;
                        acc4[t].z += v.z; acc4[t].w += v.w;
                    }
                }
            }
        }
        float4 tot;
        tot.x = (acc4[0].x + acc4[1].x) + (acc4[2].x + acc4[3].x);
        tot.y = (acc4[0].y + acc4[1].y) + (acc4[2].y + acc4[3].y);
        tot.z = (acc4[0].z + acc4[1].z) + (acc4[2].z + acc4[3].z);
        tot.w = (acc4[0].w + acc4[1].w) + (acc4[2].w + acc4[3].w);
        tot.x += __shfl_xor(tot.x, 16); tot.x += __shfl_xor(tot.x, 32);
        tot.y += __shfl_xor(tot.y, 16); tot.y += __shfl_xor(tot.y, 32);
        tot.z += __shfl_xor(tot.z, 16); tot.z += __shfl_xor(tot.z, 32);
        tot.w += __shfl_xor(tot.w, 16); tot.w += __shfl_xor(tot.w, 32);

        int deg = e1 - e0;
        float inv = 1.f / (float)(deg > 0 ? deg : 1);
        if (lane < 16) {
            float4 g4 = make_float4(tot.x * inv, tot.y * inv, tot.z * inv, tot.w * inv);
            *(float4*)&As[nn][l16 * 4] = g4;
        }
    }
    __syncthreads();

    // ---- Phase 2: [32x64]@Wl (A from LDS) + [32x64]@Wr (A = own-h direct from global)
    const int cg = tid & 15;
    const int rg = tid >> 4;
    const int row_a = node0 + rg * 2;
    float acc[2][4];
#pragma unroll
    for (int i = 0; i < 2; ++i)
#pragma unroll
        for (int j = 0; j < 4; ++j) acc[i][j] = 0.f;

    // half A: g @ Wl
    for (int kc = 0; kc < 64; kc += 32) {
#pragma unroll
        for (int i = 0; i < 2; ++i) {
            int vi = i * 256 + tid;
            int k = vi >> 4;
            int c = (vi & 15) << 2;
            *(float4*)&Bs[k][c] = *(const float4*)(Wl + (size_t)(kc + k) * 64 + c);
        }
        __syncthreads();
#pragma unroll
        for (int k4 = 0; k4 < 32; k4 += 4) {
            float4 a4[2];
#pragma unroll
            for (int i = 0; i < 2; ++i)
                a4[i] = *(const float4*)&As[rg * 2 + i][kc + k4];
#pragma unroll
            for (int j = 0; j < 4; ++j) {
                float4 bv = *(const float4*)&Bs[k4 + j][cg * 4];
#pragma unroll
                for (int i = 0; i < 2; ++i) {
                    float av = ((const float*)&a4[i])[j];
                    acc[i][0] = fmaf(av, bv.x, acc[i][0]);
                    acc[i][1] = fmaf(av, bv.y, acc[i][1]);
                    acc[i][2] = fmaf(av, bv.z, acc[i][2]);
                    acc[i][3] = fmaf(av, bv.w, acc[i][3]);
                }
            }
        }
        __syncthreads();
    }
    // half B: own-h @ Wr (a4 broadcast-read from global; L1-hot from gather)
    for (int kc = 0; kc < 64; kc += 32) {
#pragma unroll
        for (int i = 0; i < 2; ++i) {
            int vi = i * 256 + tid;
            int k = vi >> 4;
            int c = (vi & 15) << 2;
            *(float4*)&Bs[k][c] = *(const float4*)(Wr + (size_t)(kc + k) * 64 + c);
        }
        __syncthreads();
#pragma unroll
        for (int k4 = 0; k4 < 32; k4 += 4) {
            float4 a4[2];
#pragma unroll
            for (int i = 0; i < 2; ++i) {
                int row = row_a + i;
                a4[i] = (row < N) ? *(const float4*)(h + (size_t)row * 64 + kc + k4)
                                  : make_float4(0.f, 0.f, 0.f, 0.f);
            }
#pragma unroll
            for (int j = 0; j < 4; ++j) {
                float4 bv = *(const float4*)&Bs[k4 + j][cg * 4];
#pragma unroll
                for (int i = 0; i < 2; ++i) {
                    float av = ((const float*)&a4[i])[j];
                    acc[i][0] = fmaf(av, bv.x, acc[i][0]);
                    acc[i][1] = fmaf(av, bv.y, acc[i][1]);
                    acc[i][2] = fmaf(av, bv.z, acc[i][2]);
                    acc[i][3] = fmaf(av, bv.w, acc[i][3]);
                }
            }
        }
        __syncthreads();
    }

    float4 b4 = *(const float4*)(bias + cg * 4);

    if (!SCORER) {
#pragma unroll
        for (int i = 0; i < 2; ++i) {
            int row = row_a + i;
            if (row < N) {
                float4 o;
                o.x = fmaxf(acc[i][0] + b4.x, 0.f);
                o.y = fmaxf(acc[i][1] + b4.y, 0.f);
                o.z = fmaxf(acc[i][2] + b4.z, 0.f);
                o.w = fmaxf(acc[i][3] + b4.w, 0.f);
                *(float4*)(hout + (size_t)row * 64 + cg * 4) = o;
            }
        }
        return;
    }

    // ---- SCORER: h2 -> As cols 0..63, then s = relu(h2@w1+b1)@w2 + b2 (h2 never hits HBM)
#pragma unroll
    for (int i = 0; i < 2; ++i) {
        float4 t;
        t.x = fmaxf(acc[i][0] + b4.x, 0.f);
        t.y = fmaxf(acc[i][1] + b4.y, 0.f);
        t.z = fmaxf(acc[i][2] + b4.z, 0.f);
        t.w = fmaxf(acc[i][3] + b4.w, 0.f);
        *(float4*)&As[rg * 2 + i][cg * 4] = t;
    }

    float acc2[2][4];
#pragma unroll
    for (int i = 0; i < 2; ++i)
#pragma unroll
        for (int j = 0; j < 4; ++j) acc2[i][j] = 0.f;

    for (int kc = 0; kc < 64; kc += 32) {
#pragma unroll
        for (int i = 0; i < 2; ++i) {
            int vi = i * 256 + tid;
            int k = vi >> 4;
            int c = (vi & 15) << 2;
            *(float4*)&Bs[k][c] = *(const float4*)(sw1 + (size_t)(kc + k) * 64 + c);
        }
        __syncthreads();   // covers both the As h2-writes and the Bs staging
#pragma unroll
        for (int k4 = 0; k4 < 32; k4 += 4) {
            float4 a4[2];
#pragma unroll
            for (int i = 0; i < 2; ++i)
                a4[i] = *(const float4*)&As[rg * 2 + i][kc + k4];
#pragma unroll
            for (int j = 0; j < 4; ++j) {
                float4 bv = *(const float4*)&Bs[k4 + j][cg * 4];
#pragma unroll
                for (int i = 0; i < 2; ++i) {
                    float av = ((const float*)&a4[i])[j];
                    acc2[i][0] = fmaf(av, bv.x, acc2[i][0]);
                    acc2[i][1] = fmaf(av, bv.y, acc2[i][1]);
                    acc2[i][2] = fmaf(av, bv.z, acc2[i][2]);
                    acc2[i][3] = fmaf(av, bv.w, acc2[i][3]);
                }
            }
        }
        __syncthreads();
    }

    float4 s1b = *(const float4*)(sb1 + cg * 4);
    float4 w24 = *(const float4*)(sw2 + cg * 4);
    float bb = sb2[0];
    float svals[2];
#pragma unroll
    for (int i = 0; i < 2; ++i) {
        float p = fmaxf(acc2[i][0] + s1b.x, 0.f) * w24.x;
        p = fmaf(fmaxf(acc2[i][1] + s1b.y, 0.f), w24.y, p);
        p = fmaf(fmaxf(acc2[i][2] + s1b.z, 0.f), w24.z, p);
        p = fmaf(fmaxf(acc2[i][3] + s1b.w, 0.f), w24.w, p);
#pragma unroll
        for (int d = 1; d <= 8; d <<= 1) p += __shfl_xor(p, d, 64);  // within 16-lane group
        svals[i] = p;
    }
    // block max via wave shfl + per-wave atomicMax (no LDS)
    float smx = -FLT_MAX;
#pragma unroll
    for (int i = 0; i < 2; ++i) {
        int row = row_a + i;
        float s = svals[i] + bb;
        if (row < N) {
            if (cg == 0) sbuf[row] = s;
            smx = fmaxf(smx, s);
        }
    }
#pragma unroll
    for (int d = 1; d <= 32; d <<= 1) smx = fmaxf(smx, __shfl_xor(smx, d, 64));
    if (lane == 0) atomicMax(red, enc_f(smx));
}

// ---------------- softmax: sum + finalize in ONE kernel (ticket spin, 128 resident blocks) ----
__global__ __launch_bounds__(256) void sumfinal_kernel(const float* __restrict__ s, const float* __restrict__ pos,
                                                       unsigned* __restrict__ red, float* __restrict__ out, int N)
{
    float mx = dec_f(red[0]);
    float se = 0.f, px = 0.f, py = 0.f;
    for (int i = blockIdx.x * blockDim.x + threadIdx.x; i < N; i += gridDim.x * blockDim.x) {
        float e = expf(s[i] - mx);
        se += e;
        px = fmaf(e, pos[2 * i], px);
        py = fmaf(e, pos[2 * i + 1], py);
    }
#pragma unroll
    for (int d = 32; d >= 1; d >>= 1) {
        se += __shfl_xor(se, d, 64);
        px += __shfl_xor(px, d, 64);
        py += __shfl_xor(py, d, 64);
    }
    if ((threadIdx.x & 63) == 0) {
        atomicAdd((float*)red + 1, se);
        atomicAdd((float*)red + 2, px);
        atomicAdd((float*)red + 3, py);
    }
    __threadfence();
    if (threadIdx.x == 0) {
        __hip_atomic_fetch_add(&red[4], 1u, __ATOMIC_ACQ_REL, __HIP_MEMORY_SCOPE_AGENT);
        while (__hip_atomic_load(&red[4], __ATOMIC_ACQUIRE, __HIP_MEMORY_SCOPE_AGENT) < (unsigned)gridDim.x) {}
    }
    __syncthreads();
    float S  = __uint_as_float(__hip_atomic_load(&red[1], __ATOMIC_RELAXED, __HIP_MEMORY_SCOPE_AGENT));
    float PX = __uint_as_float(__hip_atomic_load(&red[2], __ATOMIC_RELAXED, __HIP_MEMORY_SCOPE_AGENT));
    float PY = __uint_as_float(__hip_atomic_load(&red[3], __ATOMIC_RELAXED, __HIP_MEMORY_SCOPE_AGENT));
    float invS = 1.f / S;
    for (int i = blockIdx.x * blockDim.x + threadIdx.x; i < N; i += gridDim.x * blockDim.x)
        out[2 + i] = expf(s[i] - mx) * invS;
    if (blockIdx.x == 0 && threadIdx.x == 0) {
        out[0] = PX * invS;
        out[1] = PY * invS;
    }
}

extern "C" void kernel_launch(void* const* d_in, const int* in_sizes, int n_in,
                              void* d_out, int out_size, void* d_ws, size_t ws_size,
                              hipStream_t stream)
{
    const float* x    = (const float*)d_in[0];
    const float* pos  = (const float*)d_in[1];
    const int*   ei   = (const int*)d_in[2];
    const int*   qids = (const int*)d_in[3];
    const float* qrs  = (const float*)d_in[4];
    const float* emb  = (const float*)d_in[5];
    const float* ew   = (const float*)d_in[6];
    const float* eb   = (const float*)d_in[7];
    const float* Wl0  = (const float*)d_in[8];
    const float* Wr0  = (const float*)d_in[9];
    const float* b0   = (const float*)d_in[10];
    const float* Wl1  = (const float*)d_in[11];
    const float* Wr1  = (const float*)d_in[12];
    const float* b1   = (const float*)d_in[13];
    const float* Wl2  = (const float*)d_in[14];
    const float* Wr2  = (const float*)d_in[15];
    const float* b2   = (const float*)d_in[16];
    const float* sw1  = (const float*)d_in[17];
    const float* sb1  = (const float*)d_in[18];
    const float* sw2  = (const float*)d_in[19];
    const float* sb2  = (const float*)d_in[20];

    const int N  = in_sizes[0] / 128;
    const int E  = in_sizes[2] / 2;
    const int NQ = in_sizes[3];
    const int NB = (N + 255) / 256;

    char* base = (char*)d_ws;
    size_t wsoff = 0;
    auto take = [&](size_t bytes) -> char* {
        char* p = base + wsoff;
        wsoff = (wsoff + bytes + 255) & ~(size_t)255;
        return p;
    };
    int*      deg    = (int*)take((size_t)N * 4);
    int*      offs   = (int*)take((size_t)(N + 1) * 4);
    int*      rank   = (int*)take((size_t)E * 4);
    int*      bsum   = (int*)take((size_t)NB * 4);
    int*      srcs   = (int*)take((size_t)E * 4);
    float*    zout   = (float*)take(192 * 4);   // zq[64], cl[64], crb[64]
    unsigned* red    = (unsigned*)take(32);     // [0]=max [1]=sumexp [2]=px [3]=py [4]=ticket
    float*    mbuf   = (float*)take((size_t)N * 64 * 4);
    float*    rbuf   = (float*)take((size_t)N * 64 * 4);
    float*    hbuf   = (float*)take((size_t)N * 64 * 4);
    float*    sbuf   = (float*)take((size_t)N * 4);
    (void)ws_size; (void)n_in; (void)out_size;

    const int* esrc = ei;
    const int* edst = ei + E;

    hipMemsetAsync(deg, 0, (size_t)N * 4, stream);

    int schunks = (E + 4095) / 4096;
    int nCount = schunks * 8;
    enc_count_kernel<<<nCount + 1, 256, 0, stream>>>(edst, deg, rank, E, N, nCount,
                                                     qids, qrs, emb, ew, eb, Wl0, Wr0, b0, zout, NQ);
    scanA_kernel<<<NB, 256, 0, stream>>>(deg, offs, bsum, red, N);
    scanC_kernel<<<NB, 256, 0, stream>>>(offs, bsum, N, NB);

    int g64 = (N + 63) / 64;
    int g32 = (N + 31) / 32;
    // layer-0 GEMM + atomic-free scatter in one launch (independent work)
    scatter_gemm0_kernel<<<g64 + schunks, 256, 0, stream>>>(esrc, edst, rank, offs, srcs, E, N,
                                                            x, Wl0, Wr0, zout + 128, mbuf, rbuf, g64);
    // layer 0 aggregation
    agg_kernel<<<g64, 256, 0, stream>>>(mbuf, rbuf, offs, srcs, zout + 64, hbuf, N);
    // layer 1: fused agg-first + gemm (hbuf -> mbuf)
    sage_fused_kernel<false><<<g32, 256, 0, stream>>>(hbuf, offs, srcs, Wl1, Wr1, b1,
                                                      nullptr, nullptr, nullptr, nullptr,
                                                      mbuf, nullptr, nullptr, N);
    // layer 2 + scorer fused (mbuf -> sbuf, red[0])
    sage_fused_kernel<true><<<g32, 256, 0, stream>>>(mbuf, offs, srcs, Wl2, Wr2, b2,
                                                     sw1, sb1, sw2, sb2,
                                                     nullptr, sbuf, red, N);
    // softmax sum + finalize (single launch, internal grid sync)
    sumfinal_kernel<<<128, 256, 0, stream>>>(sbuf, pos, red, (float*)d_out, N);
}

// Round 7
// 431.696 us; speedup vs baseline: 2.0252x; 2.0252x over previous
//
#include <hip/hip_runtime.h>
#include <cmath>
#include <cfloat>

#define DEV __device__ __forceinline__

DEV unsigned enc_f(float x) { unsigned u = __float_as_uint(x); return (u >> 31) ? ~u : (u | 0x80000000u); }
DEV float dec_f(unsigned u) { return __uint_as_float((u >> 31) ? (u & 0x7FFFFFFFu) : ~u); }

// ---------------- XCD-partitioned degree count + rank capture (+ encoder in last block) -------
// rank[i] = # of earlier-processed edges with the same dst -> scatter needs no atomics.
__global__ __launch_bounds__(256) void enc_count_kernel(
    const int* __restrict__ dst, int* __restrict__ deg, int* __restrict__ rank,
    int E, int N, int nCount,
    const int* __restrict__ ids, const float* __restrict__ rssi,
    const float* __restrict__ emb, const float* __restrict__ ew, const float* __restrict__ eb,
    const float* __restrict__ Wl0, const float* __restrict__ Wr0, const float* __restrict__ b0,
    float* __restrict__ zout, int NQ)
{
    if (blockIdx.x < (unsigned)nCount) {
        const int part = blockIdx.x & 7;
        const int chunk = blockIdx.x >> 3;
        const int npart = (N + 7) >> 3;
        const int lo = part * npart;
        const int hi = min(lo + npart, N);
        const int base = chunk * 4096 + threadIdx.x;
#pragma unroll
        for (int it = 0; it < 16; ++it) {
            int i = base + it * 256;
            if (i < E) {
                int d = dst[i];
                if (d >= lo && d < hi) rank[i] = atomicAdd(&deg[d], 1);
            }
        }
        return;
    }
    __shared__ float zsh[4][64];
    __shared__ float zq[64];
    int j = threadIdx.x & 63;
    int g = threadIdx.x >> 6;
    float acc = 0.f;
    for (int q = g; q < NQ; q += 4) {
        int id = ids[q];
        const float* e = emb + (size_t)id * 32;
        float p = eb[j];
#pragma unroll
        for (int k = 0; k < 32; ++k) p = fmaf(e[k], ew[k * 64 + j], p);
        p = fmaf(rssi[q], ew[32 * 64 + j], p);
        acc += fmaxf(p, 0.f);
    }
    zsh[g][j] = acc;
    __syncthreads();
    if (g == 0) {
        float z = (zsh[0][j] + zsh[1][j] + zsh[2][j] + zsh[3][j]) / (float)NQ;
        zq[j] = z;
        zout[j] = z;
    }
    __syncthreads();
    if (g == 0) {
        float cl = 0.f, cr = 0.f;
        for (int k = 0; k < 64; ++k) {
            float zk = zq[k];
            cl = fmaf(zk, Wl0[(128 + k) * 64 + j], cl);
            cr = fmaf(zk, Wr0[(128 + k) * 64 + j], cr);
        }
        zout[64 + j] = cl;
        zout[128 + j] = cr + b0[j];
    }
}

// ---------------- CSR build: scanA (local) + scanC (per-block prefix of bsum) ----------------
__global__ __launch_bounds__(256) void scanA_kernel(const int* __restrict__ deg, int* __restrict__ offs,
                                                    int* __restrict__ bsum, unsigned* __restrict__ red, int N)
{
    __shared__ int sh[256];
    int t = threadIdx.x;
    if (blockIdx.x == 0 && t < 8) red[t] = 0u;
    int i = blockIdx.x * 256 + t;
    int v = (i < N) ? deg[i] : 0;
    sh[t] = v;
    __syncthreads();
#pragma unroll
    for (int d = 1; d < 256; d <<= 1) {
        int u = (t >= d) ? sh[t - d] : 0;
        __syncthreads();
        sh[t] += u;
        __syncthreads();
    }
    if (i < N) offs[i] = sh[t] - v;
    if (t == 255) bsum[blockIdx.x] = sh[255];
}

// Each block recomputes its exclusive prefix over bsum (NB<=256 values) -> no scanB launch.
__global__ __launch_bounds__(256) void scanC_kernel(int* __restrict__ offs, const int* __restrict__ bsum,
                                                    int N, int NB)
{
    __shared__ int sh[256];
    int t = threadIdx.x;
    int bid = blockIdx.x;
    int s = 0;
    for (int j = t; j < bid; j += 256) s += bsum[j];
    sh[t] = s;
    __syncthreads();
#pragma unroll
    for (int d = 128; d >= 1; d >>= 1) {
        if (t < d) sh[t] += sh[t + d];
        __syncthreads();
    }
    int base = sh[0];
    int i = bid * 256 + t;
    if (i < N) offs[i] += base;
    if (bid == NB - 1 && t == 0) offs[N] = base + bsum[NB - 1];
}

// ---------------- combined: atomic-free scatter + layer-0 GEMM (independent work) ------------
__global__ __launch_bounds__(256) void scatter_gemm0_kernel(
    const int* __restrict__ src, const int* __restrict__ dst,
    const int* __restrict__ rank, const int* __restrict__ offs,
    int* __restrict__ srcs, int E, int N,
    const float* __restrict__ A, const float* __restrict__ B1, const float* __restrict__ B2,
    const float* __restrict__ add2, float* __restrict__ O1, float* __restrict__ O2, int nGemm)
{
    __shared__ float As[64][36];    // 9.2 KB
    __shared__ float Bs[32][128];   // 16.4 KB

    if (blockIdx.x >= (unsigned)nGemm) {
        const int chunk = blockIdx.x - nGemm;
        const int base = chunk * 4096 + threadIdx.x;
#pragma unroll
        for (int it = 0; it < 16; ++it) {
            int i = base + it * 256;
            if (i < E) {
                int d = dst[i];
                srcs[offs[d] + rank[i]] = src[i];
            }
        }
        return;
    }

    const int tid = threadIdx.x;
    const int cg = tid & 15;        // 16 col groups x 8 cols = 128
    const int rg = tid >> 4;        // 16 row groups x 4 rows = 64
    const int row0 = blockIdx.x * 64;

    float acc[4][8];
#pragma unroll
    for (int i = 0; i < 4; ++i)
#pragma unroll
        for (int j = 0; j < 8; ++j) acc[i][j] = 0.f;

    for (int kc = 0; kc < 128; kc += 32) {
#pragma unroll
        for (int i = 0; i < 2; ++i) {
            int vi = i * 256 + tid;
            int r = vi >> 3;
            int k4 = (vi & 7) << 2;
            int row = row0 + r;
            float4 v = make_float4(0.f, 0.f, 0.f, 0.f);
            if (row < N) v = *(const float4*)(A + (size_t)row * 128 + kc + k4);
            *(float4*)&As[r][k4] = v;
        }
#pragma unroll
        for (int i = 0; i < 4; ++i) {
            int vi = i * 256 + tid;
            int k = vi >> 5;
            int c = (vi & 31) << 2;
            const float* sp = (c < 64) ? (B1 + (size_t)(kc + k) * 64 + c)
                                       : (B2 + (size_t)(kc + k) * 64 + (c - 64));
            *(float4*)&Bs[k][c] = *(const float4*)sp;
        }
        __syncthreads();
#pragma unroll
        for (int k4 = 0; k4 < 32; k4 += 4) {
            float4 a4[4];
#pragma unroll
            for (int i = 0; i < 4; ++i)
                a4[i] = *(const float4*)&As[rg * 4 + i][k4];
#pragma unroll
            for (int j = 0; j < 4; ++j) {
                float4 b0v = *(const float4*)&Bs[k4 + j][cg * 8];
                float4 b1v = *(const float4*)&Bs[k4 + j][cg * 8 + 4];
#pragma unroll
                for (int i = 0; i < 4; ++i) {
                    float av = ((const float*)&a4[i])[j];
                    acc[i][0] = fmaf(av, b0v.x, acc[i][0]);
                    acc[i][1] = fmaf(av, b0v.y, acc[i][1]);
                    acc[i][2] = fmaf(av, b0v.z, acc[i][2]);
                    acc[i][3] = fmaf(av, b0v.w, acc[i][3]);
                    acc[i][4] = fmaf(av, b1v.x, acc[i][4]);
                    acc[i][5] = fmaf(av, b1v.y, acc[i][5]);
                    acc[i][6] = fmaf(av, b1v.z, acc[i][6]);
                    acc[i][7] = fmaf(av, b1v.w, acc[i][7]);
                }
            }
        }
        __syncthreads();
    }

    int c0 = cg * 8;
    float* O; int c; const float* addp = nullptr;
    if (c0 < 64) { O = O1; c = c0; }
    else         { O = O2; c = c0 - 64; addp = add2; }
    float4 av0 = make_float4(0.f, 0.f, 0.f, 0.f), av1 = av0;
    if (addp) { av0 = *(const float4*)(addp + c); av1 = *(const float4*)(addp + c + 4); }
#pragma unroll
    for (int i = 0; i < 4; ++i) {
        int row = row0 + rg * 4 + i;
        if (row < N) {
            float4 o0, o1;
            o0.x = acc[i][0] + av0.x; o0.y = acc[i][1] + av0.y;
            o0.z = acc[i][2] + av0.z; o0.w = acc[i][3] + av0.w;
            o1.x = acc[i][4] + av1.x; o1.y = acc[i][5] + av1.y;
            o1.z = acc[i][6] + av1.z; o1.w = acc[i][7] + av1.w;
            *(float4*)(O + (size_t)row * 64 + c) = o0;
            *(float4*)(O + (size_t)row * 64 + c + 4) = o1;
        }
    }
}

// ---------------- layer-0 aggregation (float4 16-lane gather, no LDS -> max occupancy) -------
__global__ __launch_bounds__(256) void agg_kernel(
    const float* __restrict__ m, const float* __restrict__ r,
    const int* __restrict__ off, const int* __restrict__ srcs,
    const float* __restrict__ cl, float* __restrict__ hout, int N)
{
    const int tid = threadIdx.x;
    const int lane = tid & 63;
    const int wave = tid >> 6;
    const int grp = lane >> 4;
    const int l16 = lane & 15;
    const int node0 = blockIdx.x * 64;

    int offv = off[min(node0 + lane, N)];
    int offend = off[min(node0 + 64, N)];
    float4 cl4 = *(const float4*)(cl + l16 * 4);

    int e0p = __shfl(offv, wave);
    int e1p = (wave < 63) ? __shfl(offv, wave + 1) : offend;
    int sv = (e0p + lane < e1p) ? srcs[e0p + lane] : 0;

    for (int idx = 0; idx < 16; ++idx) {
        int nn = wave + idx * 4;
        int node = node0 + nn;
        int e0 = __shfl(offv, nn);
        int e1 = (nn < 63) ? __shfl(offv, nn + 1) : offend;
        int cur_sv = sv;
        if (idx < 15) {
            int nx = nn + 4;
            int ne0 = __shfl(offv, nx);
            int ne1 = (nx < 63) ? __shfl(offv, nx + 1) : offend;
            sv = (ne0 + lane < ne1) ? srcs[ne0 + lane] : 0;
        }
        float4 r4 = make_float4(0.f, 0.f, 0.f, 0.f);
        if (node < N) r4 = *((const float4*)(r + (size_t)node * 64) + l16);

        float4 acc4[4];
#pragma unroll
        for (int t = 0; t < 4; ++t) acc4[t] = make_float4(0.f, 0.f, 0.f, 0.f);

        for (int base = e0; base < e1; base += 64) {
            int cnt = min(e1 - base, 64);
            int svs = (base == e0) ? cur_sv : ((base + lane < e1) ? srcs[base + lane] : 0);
            for (int u = 0; u < cnt; u += 16) {
#pragma unroll
                for (int t = 0; t < 4; ++t) {
                    int ei = u + t * 4 + grp;
                    int s = __shfl(svs, ei);
                    if (ei < cnt) {
                        float4 v = *((const float4*)(m + (size_t)s * 64) + l16);
                        acc4[t].x += v.x; acc4[t].y += v.y;
                        acc4[t].z += v.z; acc4[t].w += v.w;
                    }
                }
            }
        }
        float4 tot;
        tot.x = (acc4[0].x + acc4[1].x) + (acc4[2].x + acc4[3].x);
        tot.y = (acc4[0].y + acc4[1].y) + (acc4[2].y + acc4[3].y);
        tot.z = (acc4[0].z + acc4[1].z) + (acc4[2].z + acc4[3].z);
        tot.w = (acc4[0].w + acc4[1].w) + (acc4[2].w + acc4[3].w);
        tot.x += __shfl_xor(tot.x, 16); tot.x += __shfl_xor(tot.x, 32);
        tot.y += __shfl_xor(tot.y, 16); tot.y += __shfl_xor(tot.y, 32);
        tot.z += __shfl_xor(tot.z, 16); tot.z += __shfl_xor(tot.z, 32);
        tot.w += __shfl_xor(tot.w, 16); tot.w += __shfl_xor(tot.w, 32);

        int deg = e1 - e0;
        float inv = 1.f / (float)(deg > 0 ? deg : 1);
        if (lane < 16 && node < N) {
            float cadd = (deg > 0) ? 1.f : 0.f;
            float4 o;
            o.x = fmaxf(fmaf(tot.x, inv, fmaf(cadd, cl4.x, r4.x)), 0.f);
            o.y = fmaxf(fmaf(tot.y, inv, fmaf(cadd, cl4.y, r4.y)), 0.f);
            o.z = fmaxf(fmaf(tot.z, inv, fmaf(cadd, cl4.z, r4.z)), 0.f);
            o.w = fmaxf(fmaf(tot.w, inv, fmaf(cadd, cl4.w, r4.w)), 0.f);
            *(float4*)(hout + (size_t)node * 64 + l16 * 4) = o;
        }
    }
}

// ---------------- fused SAGE layer (layers 1-2): round-4 dataflow, 18.9 KB LDS ---------------
// Identical gather + LDS-GEMM structure to the verified 385us round-4 kernel (52 VGPR).
// Only LDS shaved: Bs staged 8 k-rows/chunk (2 KB) and smax tree -> wave shfl+atomicMax.
// 18.9 KB -> 8 blocks/CU (32 waves, HW max). Gather is concurrency-bound; this is the lever.
template <bool SCORER>
__global__ __launch_bounds__(256) void sage_fused_kernel(
    const float* __restrict__ h,
    const int* __restrict__ off, const int* __restrict__ srcs,
    const float* __restrict__ Wl, const float* __restrict__ Wr, const float* __restrict__ bias,
    const float* __restrict__ sw1, const float* __restrict__ sb1,
    const float* __restrict__ sw2, const float* __restrict__ sb2,
    float* __restrict__ hout, float* __restrict__ sbuf, unsigned* __restrict__ red, int N)
{
    __shared__ float As[32][132];   // 16.9 KB: [gathered-mean | own-h] per node
    __shared__ float Bs[8][64];     // 2 KB weight chunk (8 k-rows)

    const int tid = threadIdx.x;
    const int lane = tid & 63;
    const int wave = tid >> 6;
    const int grp = lane >> 4;
    const int l16 = lane & 15;
    const int node0 = blockIdx.x * 32;

    int offv = off[min(node0 + lane, N)];   // lanes 0..32 used

    // ---- Phase 1: gather (8 nodes per wave), float4 lanes: 4 edge-rows per wave-load
    int e0p = __shfl(offv, wave);
    int e1p = __shfl(offv, wave + 1);
    int sv = (e0p + lane < e1p) ? srcs[e0p + lane] : 0;

    for (int idx = 0; idx < 8; ++idx) {
        int nn = wave + idx * 4;
        int node = node0 + nn;
        int e0 = __shfl(offv, nn);
        int e1 = __shfl(offv, nn + 1);
        int cur_sv = sv;
        if (idx < 7) {
            int nx = nn + 4;
            int ne0 = __shfl(offv, nx);
            int ne1 = __shfl(offv, nx + 1);
            sv = (ne0 + lane < ne1) ? srcs[ne0 + lane] : 0;
        }
        float4 hv = make_float4(0.f, 0.f, 0.f, 0.f);
        if (node < N) hv = *((const float4*)(h + (size_t)node * 64) + l16);

        float4 acc4[4];
#pragma unroll
        for (int t = 0; t < 4; ++t) acc4[t] = make_float4(0.f, 0.f, 0.f, 0.f);

        for (int base = e0; base < e1; base += 64) {
            int cnt = min(e1 - base, 64);
            int svs = (base == e0) ? cur_sv : ((base + lane < e1) ? srcs[base + lane] : 0);
            for (int u = 0; u < cnt; u += 16) {
#pragma unroll
                for (int t = 0; t < 4; ++t) {
                    int ei = u + t * 4 + grp;
                    int s = __shfl(svs, ei);
                    if (ei < cnt) {
                        float4 v = *((const float4*)(h + (size_t)s * 64) + l16);
                        acc4[t].x += v.x; acc4[t].y += v.y;
                        acc4[t].z += v.z; acc4[t].w += v.w;
                    }
                }
            }
        }
        float4 tot;
        tot.x = (acc4[0].x + acc4[1].x) + (acc4[2].x + acc4[3].x);
        tot.y = (acc4[0].y + acc4[1].y) + (acc4[2].y + acc4[3].y);
        tot.z = (acc4[0].z + acc4[1].z) + (acc4[2].z + acc4[3].z);
        tot.w = (acc4[0].w + acc4[1].w) + (acc4[2].w + acc4[3].w);
        tot.x += __shfl_xor(tot.x, 16); tot.x += __shfl_xor(tot.x, 32);
        tot.y += __shfl_xor(tot.y, 16); tot.y += __shfl_xor(tot.y, 32);
        tot.z += __shfl_xor(tot.z, 16); tot.z += __shfl_xor(tot.z, 32);
        tot.w += __shfl_xor(tot.w, 16); tot.w += __shfl_xor(tot.w, 32);

        int deg = e1 - e0;
        float inv = 1.f / (float)(deg > 0 ? deg : 1);
        if (lane < 16) {
            float4 g4 = make_float4(tot.x * inv, tot.y * inv, tot.z * inv, tot.w * inv);
            *(float4*)&As[nn][l16 * 4] = g4;
            *(float4*)&As[nn][64 + l16 * 4] = hv;
        }
    }

    // ---- Phase 2: [32x128] @ [128x64], thread tile 2 rows x 4 cols; Bs = 8 k-rows/chunk
    const int cg = tid & 15;
    const int rg = tid >> 4;
    float acc[2][4];
#pragma unroll
    for (int i = 0; i < 2; ++i)
#pragma unroll
        for (int j = 0; j < 4; ++j) acc[i][j] = 0.f;

    for (int kc = 0; kc < 128; kc += 8) {
        {
            int k = tid >> 5;            // 8 rows x 32 threads
            int c = (tid & 31) << 1;     // 2 cols each
            int kg = kc + k;
            const float* wp = (kg < 64) ? (Wl + (size_t)kg * 64 + c)
                                        : (Wr + (size_t)(kg - 64) * 64 + c);
            *(float2*)&Bs[k][c] = *(const float2*)wp;
        }
        __syncthreads();
#pragma unroll
        for (int k4 = 0; k4 < 8; k4 += 4) {
            float4 a4[2];
#pragma unroll
            for (int i = 0; i < 2; ++i)
                a4[i] = *(const float4*)&As[rg * 2 + i][kc + k4];   // broadcast
#pragma unroll
            for (int j = 0; j < 4; ++j) {
                float4 bv = *(const float4*)&Bs[k4 + j][cg * 4];
#pragma unroll
                for (int i = 0; i < 2; ++i) {
                    float av = ((const float*)&a4[i])[j];
                    acc[i][0] = fmaf(av, bv.x, acc[i][0]);
                    acc[i][1] = fmaf(av, bv.y, acc[i][1]);
                    acc[i][2] = fmaf(av, bv.z, acc[i][2]);
                    acc[i][3] = fmaf(av, bv.w, acc[i][3]);
                }
            }
        }
        __syncthreads();
    }

    float4 b4 = *(const float4*)(bias + cg * 4);

    if (!SCORER) {
#pragma unroll
        for (int i = 0; i < 2; ++i) {
            int row = node0 + rg * 2 + i;
            if (row < N) {
                float4 o;
                o.x = fmaxf(acc[i][0] + b4.x, 0.f);
                o.y = fmaxf(acc[i][1] + b4.y, 0.f);
                o.z = fmaxf(acc[i][2] + b4.z, 0.f);
                o.w = fmaxf(acc[i][3] + b4.w, 0.f);
                *(float4*)(hout + (size_t)row * 64 + cg * 4) = o;
            }
        }
        return;
    }

    // ---- SCORER: h2 -> As cols 0..63, then s = relu(h2@w1+b1)@w2 + b2 (h2 never hits HBM)
#pragma unroll
    for (int i = 0; i < 2; ++i) {
        float4 t;
        t.x = fmaxf(acc[i][0] + b4.x, 0.f);
        t.y = fmaxf(acc[i][1] + b4.y, 0.f);
        t.z = fmaxf(acc[i][2] + b4.z, 0.f);
        t.w = fmaxf(acc[i][3] + b4.w, 0.f);
        *(float4*)&As[rg * 2 + i][cg * 4] = t;
    }
    __syncthreads();

    float acc2[2][4];
#pragma unroll
    for (int i = 0; i < 2; ++i)
#pragma unroll
        for (int j = 0; j < 4; ++j) acc2[i][j] = 0.f;

    for (int kc = 0; kc < 64; kc += 8) {
        {
            int k = tid >> 5;
            int c = (tid & 31) << 1;
            *(float2*)&Bs[k][c] = *(const float2*)(sw1 + (size_t)(kc + k) * 64 + c);
        }
        __syncthreads();
#pragma unroll
        for (int k4 = 0; k4 < 8; k4 += 4) {
            float4 a4[2];
#pragma unroll
            for (int i = 0; i < 2; ++i)
                a4[i] = *(const float4*)&As[rg * 2 + i][kc + k4];
#pragma unroll
            for (int j = 0; j < 4; ++j) {
                float4 bv = *(const float4*)&Bs[k4 + j][cg * 4];
#pragma unroll
                for (int i = 0; i < 2; ++i) {
                    float av = ((const float*)&a4[i])[j];
                    acc2[i][0] = fmaf(av, bv.x, acc2[i][0]);
                    acc2[i][1] = fmaf(av, bv.y, acc2[i][1]);
                    acc2[i][2] = fmaf(av, bv.z, acc2[i][2]);
                    acc2[i][3] = fmaf(av, bv.w, acc2[i][3]);
                }
            }
        }
        __syncthreads();
    }

    float4 s1b = *(const float4*)(sb1 + cg * 4);
    float4 w24 = *(const float4*)(sw2 + cg * 4);
    float bb = sb2[0];
    float svals[2];
#pragma unroll
    for (int i = 0; i < 2; ++i) {
        float p = fmaxf(acc2[i][0] + s1b.x, 0.f) * w24.x;
        p = fmaf(fmaxf(acc2[i][1] + s1b.y, 0.f), w24.y, p);
        p = fmaf(fmaxf(acc2[i][2] + s1b.z, 0.f), w24.z, p);
        p = fmaf(fmaxf(acc2[i][3] + s1b.w, 0.f), w24.w, p);
#pragma unroll
        for (int d = 1; d <= 8; d <<= 1) p += __shfl_xor(p, d, 64);  // within 16-lane group
        svals[i] = p;
    }
    // block max via wave shfl + per-wave atomicMax (no LDS)
    float smx = -FLT_MAX;
#pragma unroll
    for (int i = 0; i < 2; ++i) {
        int row = node0 + rg * 2 + i;
        float s = svals[i] + bb;
        if (row < N) {
            if (cg == 0) sbuf[row] = s;
            smx = fmaxf(smx, s);
        }
    }
#pragma unroll
    for (int d = 1; d <= 32; d <<= 1) smx = fmaxf(smx, __shfl_xor(smx, d, 64));
    if (lane == 0) atomicMax(red, enc_f(smx));
}

// ---------------- softmax: sum + finalize in ONE kernel (ticket spin, 128 resident blocks) ----
__global__ __launch_bounds__(256) void sumfinal_kernel(const float* __restrict__ s, const float* __restrict__ pos,
                                                       unsigned* __restrict__ red, float* __restrict__ out, int N)
{
    float mx = dec_f(red[0]);
    float se = 0.f, px = 0.f, py = 0.f;
    for (int i = blockIdx.x * blockDim.x + threadIdx.x; i < N; i += gridDim.x * blockDim.x) {
        float e = expf(s[i] - mx);
        se += e;
        px = fmaf(e, pos[2 * i], px);
        py = fmaf(e, pos[2 * i + 1], py);
    }
#pragma unroll
    for (int d = 32; d >= 1; d >>= 1) {
        se += __shfl_xor(se, d, 64);
        px += __shfl_xor(px, d, 64);
        py += __shfl_xor(py, d, 64);
    }
    if ((threadIdx.x & 63) == 0) {
        atomicAdd((float*)red + 1, se);
        atomicAdd((float*)red + 2, px);
        atomicAdd((float*)red + 3, py);
    }
    __threadfence();
    if (threadIdx.x == 0) {
        __hip_atomic_fetch_add(&red[4], 1u, __ATOMIC_ACQ_REL, __HIP_MEMORY_SCOPE_AGENT);
        while (__hip_atomic_load(&red[4], __ATOMIC_ACQUIRE, __HIP_MEMORY_SCOPE_AGENT) < (unsigned)gridDim.x) {}
    }
    __syncthreads();
    float S  = __uint_as_float(__hip_atomic_load(&red[1], __ATOMIC_RELAXED, __HIP_MEMORY_SCOPE_AGENT));
    float PX = __uint_as_float(__hip_atomic_load(&red[2], __ATOMIC_RELAXED, __HIP_MEMORY_SCOPE_AGENT));
    float PY = __uint_as_float(__hip_atomic_load(&red[3], __ATOMIC_RELAXED, __HIP_MEMORY_SCOPE_AGENT));
    float invS = 1.f / S;
    for (int i = blockIdx.x * blockDim.x + threadIdx.x; i < N; i += gridDim.x * blockDim.x)
        out[2 + i] = expf(s[i] - mx) * invS;
    if (blockIdx.x == 0 && threadIdx.x == 0) {
        out[0] = PX * invS;
        out[1] = PY * invS;
    }
}

extern "C" void kernel_launch(void* const* d_in, const int* in_sizes, int n_in,
                              void* d_out, int out_size, void* d_ws, size_t ws_size,
                              hipStream_t stream)
{
    const float* x    = (const float*)d_in[0];
    const float* pos  = (const float*)d_in[1];
    const int*   ei   = (const int*)d_in[2];
    const int*   qids = (const int*)d_in[3];
    const float* qrs  = (const float*)d_in[4];
    const float* emb  = (const float*)d_in[5];
    const float* ew   = (const float*)d_in[6];
    const float* eb   = (const float*)d_in[7];
    const float* Wl0  = (const float*)d_in[8];
    const float* Wr0  = (const float*)d_in[9];
    const float* b0   = (const float*)d_in[10];
    const float* Wl1  = (const float*)d_in[11];
    const float* Wr1  = (const float*)d_in[12];
    const float* b1   = (const float*)d_in[13];
    const float* Wl2  = (const float*)d_in[14];
    const float* Wr2  = (const float*)d_in[15];
    const float* b2   = (const float*)d_in[16];
    const float* sw1  = (const float*)d_in[17];
    const float* sb1  = (const float*)d_in[18];
    const float* sw2  = (const float*)d_in[19];
    const float* sb2  = (const float*)d_in[20];

    const int N  = in_sizes[0] / 128;
    const int E  = in_sizes[2] / 2;
    const int NQ = in_sizes[3];
    const int NB = (N + 255) / 256;

    char* base = (char*)d_ws;
    size_t wsoff = 0;
    auto take = [&](size_t bytes) -> char* {
        char* p = base + wsoff;
        wsoff = (wsoff + bytes + 255) & ~(size_t)255;
        return p;
    };
    int*      deg    = (int*)take((size_t)N * 4);
    int*      offs   = (int*)take((size_t)(N + 1) * 4);
    int*      rank   = (int*)take((size_t)E * 4);
    int*      bsum   = (int*)take((size_t)NB * 4);
    int*      srcs   = (int*)take((size_t)E * 4);
    float*    zout   = (float*)take(192 * 4);   // zq[64], cl[64], crb[64]
    unsigned* red    = (unsigned*)take(32);     // [0]=max [1]=sumexp [2]=px [3]=py [4]=ticket
    float*    mbuf   = (float*)take((size_t)N * 64 * 4);
    float*    rbuf   = (float*)take((size_t)N * 64 * 4);
    float*    hbuf   = (float*)take((size_t)N * 64 * 4);
    float*    sbuf   = (float*)take((size_t)N * 4);
    (void)ws_size; (void)n_in; (void)out_size;

    const int* esrc = ei;
    const int* edst = ei + E;

    hipMemsetAsync(deg, 0, (size_t)N * 4, stream);

    int schunks = (E + 4095) / 4096;
    int nCount = schunks * 8;
    enc_count_kernel<<<nCount + 1, 256, 0, stream>>>(edst, deg, rank, E, N, nCount,
                                                     qids, qrs, emb, ew, eb, Wl0, Wr0, b0, zout, NQ);
    scanA_kernel<<<NB, 256, 0, stream>>>(deg, offs, bsum, red, N);
    scanC_kernel<<<NB, 256, 0, stream>>>(offs, bsum, N, NB);

    int g64 = (N + 63) / 64;
    int g32 = (N + 31) / 32;
    // layer-0 GEMM + atomic-free scatter in one launch (independent work)
    scatter_gemm0_kernel<<<g64 + schunks, 256, 0, stream>>>(esrc, edst, rank, offs, srcs, E, N,
                                                            x, Wl0, Wr0, zout + 128, mbuf, rbuf, g64);
    // layer 0 aggregation
    agg_kernel<<<g64, 256, 0, stream>>>(mbuf, rbuf, offs, srcs, zout + 64, hbuf, N);
    // layer 1: fused agg-first + gemm (hbuf -> mbuf)
    sage_fused_kernel<false><<<g32, 256, 0, stream>>>(hbuf, offs, srcs, Wl1, Wr1, b1,
                                                      nullptr, nullptr, nullptr, nullptr,
                                                      mbuf, nullptr, nullptr, N);
    // layer 2 + scorer fused (mbuf -> sbuf, red[0])
    sage_fused_kernel<true><<<g32, 256, 0, stream>>>(mbuf, offs, srcs, Wl2, Wr2, b2,
                                                     sw1, sb1, sw2, sb2,
                                                     nullptr, sbuf, red, N);
    // softmax sum + finalize (single launch, internal grid sync)
    sumfinal_kernel<<<128, 256, 0, stream>>>(sbuf, pos, red, (float*)d_out, N);
}

// Round 8
// 380.495 us; speedup vs baseline: 2.2978x; 1.1346x over previous
//
#include <hip/hip_runtime.h>
#include <cmath>
#include <cfloat>

#define DEV __device__ __forceinline__

DEV unsigned enc_f(float x) { unsigned u = __float_as_uint(x); return (u >> 31) ? ~u : (u | 0x80000000u); }
DEV float dec_f(unsigned u) { return __uint_as_float((u >> 31) ? (u & 0x7FFFFFFFu) : ~u); }

// ---------------- merged launch 1: layer-0 GEMM + XCD-partitioned count+rank + encoder -------
// Roles by blockIdx: [0,nGemm) gemm0 (x@Wl0top -> O1, x@Wr0top -> O2, RAW, no bias);
// [nGemm, nGemm+nCount) degree count + rank capture; last block = encoder (zq, cl, crb).
// gemm0 is independent of edges/encoder -> overlaps the atomic-bound count pass.
__global__ __launch_bounds__(256) void fused0_kernel(
    const int* __restrict__ dst, int* __restrict__ deg, int* __restrict__ rank, int E, int N,
    const float* __restrict__ A, const float* __restrict__ B1, const float* __restrict__ B2,
    float* __restrict__ O1, float* __restrict__ O2, int nGemm, int nCount,
    const int* __restrict__ ids, const float* __restrict__ rssi,
    const float* __restrict__ emb, const float* __restrict__ ew, const float* __restrict__ eb,
    const float* __restrict__ b0, float* __restrict__ zout, int NQ)
{
    __shared__ float As[64][36];    // 9.2 KB
    __shared__ float Bs[32][128];   // 16.4 KB

    if (blockIdx.x >= (unsigned)nGemm) {
        if (blockIdx.x < (unsigned)(nGemm + nCount)) {
            // ---- count + rank role (XCD-partitioned by dst range)
            const int cbid = blockIdx.x - nGemm;
            const int part = cbid & 7;
            const int chunk = cbid >> 3;
            const int npart = (N + 7) >> 3;
            const int lo = part * npart;
            const int hi = min(lo + npart, N);
            const int base = chunk * 4096 + threadIdx.x;
#pragma unroll
            for (int it = 0; it < 16; ++it) {
                int i = base + it * 256;
                if (i < E) {
                    int d = dst[i];
                    if (d >= lo && d < hi) rank[i] = atomicAdd(&deg[d], 1);
                }
            }
            return;
        }
        // ---- encoder role (1 block); zsh/zq aliased into As
        float (*zsh)[64] = (float(*)[64])&As[0][0];   // 4x64 floats
        float* zq = &As[16][0];                        // past zsh
        int j = threadIdx.x & 63;
        int g = threadIdx.x >> 6;
        float acc = 0.f;
        for (int q = g; q < NQ; q += 4) {
            int id = ids[q];
            const float* e = emb + (size_t)id * 32;
            float p = eb[j];
#pragma unroll
            for (int k = 0; k < 32; ++k) p = fmaf(e[k], ew[k * 64 + j], p);
            p = fmaf(rssi[q], ew[32 * 64 + j], p);
            acc += fmaxf(p, 0.f);
        }
        zsh[g][j] = acc;
        __syncthreads();
        if (g == 0) {
            float z = (zsh[0][j] + zsh[1][j] + zsh[2][j] + zsh[3][j]) / (float)NQ;
            zq[j] = z;
            zout[j] = z;
        }
        __syncthreads();
        if (g == 0) {
            float cl = 0.f, cr = 0.f;
            for (int k = 0; k < 64; ++k) {
                float zk = zq[k];
                cl = fmaf(zk, B1[(128 + k) * 64 + j], cl);
                cr = fmaf(zk, B2[(128 + k) * 64 + j], cr);
            }
            zout[64 + j] = cl;            // cl
            zout[128 + j] = cr + b0[j];   // crb
        }
        return;
    }

    // ---- gemm0 role: 64-row dual GEMM, K=128, RAW outputs (bias/crb added later in agg)
    const int tid = threadIdx.x;
    const int cg = tid & 15;        // 16 col groups x 8 cols = 128
    const int rg = tid >> 4;        // 16 row groups x 4 rows = 64
    const int row0 = blockIdx.x * 64;

    float acc[4][8];
#pragma unroll
    for (int i = 0; i < 4; ++i)
#pragma unroll
        for (int j = 0; j < 8; ++j) acc[i][j] = 0.f;

    for (int kc = 0; kc < 128; kc += 32) {
#pragma unroll
        for (int i = 0; i < 2; ++i) {
            int vi = i * 256 + tid;
            int r = vi >> 3;
            int k4 = (vi & 7) << 2;
            int row = row0 + r;
            float4 v = make_float4(0.f, 0.f, 0.f, 0.f);
            if (row < N) v = *(const float4*)(A + (size_t)row * 128 + kc + k4);
            *(float4*)&As[r][k4] = v;
        }
#pragma unroll
        for (int i = 0; i < 4; ++i) {
            int vi = i * 256 + tid;
            int k = vi >> 5;
            int c = (vi & 31) << 2;
            const float* sp = (c < 64) ? (B1 + (size_t)(kc + k) * 64 + c)
                                       : (B2 + (size_t)(kc + k) * 64 + (c - 64));
            *(float4*)&Bs[k][c] = *(const float4*)sp;
        }
        __syncthreads();
#pragma unroll
        for (int k4 = 0; k4 < 32; k4 += 4) {
            float4 a4[4];
#pragma unroll
            for (int i = 0; i < 4; ++i)
                a4[i] = *(const float4*)&As[rg * 4 + i][k4];
#pragma unroll
            for (int j = 0; j < 4; ++j) {
                float4 b0v = *(const float4*)&Bs[k4 + j][cg * 8];
                float4 b1v = *(const float4*)&Bs[k4 + j][cg * 8 + 4];
#pragma unroll
                for (int i = 0; i < 4; ++i) {
                    float av = ((const float*)&a4[i])[j];
                    acc[i][0] = fmaf(av, b0v.x, acc[i][0]);
                    acc[i][1] = fmaf(av, b0v.y, acc[i][1]);
                    acc[i][2] = fmaf(av, b0v.z, acc[i][2]);
                    acc[i][3] = fmaf(av, b0v.w, acc[i][3]);
                    acc[i][4] = fmaf(av, b1v.x, acc[i][4]);
                    acc[i][5] = fmaf(av, b1v.y, acc[i][5]);
                    acc[i][6] = fmaf(av, b1v.z, acc[i][6]);
                    acc[i][7] = fmaf(av, b1v.w, acc[i][7]);
                }
            }
        }
        __syncthreads();
    }

    int c0 = cg * 8;
    float* O; int c;
    if (c0 < 64) { O = O1; c = c0; }
    else         { O = O2; c = c0 - 64; }
#pragma unroll
    for (int i = 0; i < 4; ++i) {
        int row = row0 + rg * 4 + i;
        if (row < N) {
            float4 o0 = make_float4(acc[i][0], acc[i][1], acc[i][2], acc[i][3]);
            float4 o1 = make_float4(acc[i][4], acc[i][5], acc[i][6], acc[i][7]);
            *(float4*)(O + (size_t)row * 64 + c) = o0;
            *(float4*)(O + (size_t)row * 64 + c + 4) = o1;
        }
    }
}

// ---------------- CSR build: scanA (local) + scanC (per-block prefix of bsum) ----------------
__global__ __launch_bounds__(256) void scanA_kernel(const int* __restrict__ deg, int* __restrict__ offs,
                                                    int* __restrict__ bsum, unsigned* __restrict__ red, int N)
{
    __shared__ int sh[256];
    int t = threadIdx.x;
    if (blockIdx.x == 0 && t < 8) red[t] = 0u;
    int i = blockIdx.x * 256 + t;
    int v = (i < N) ? deg[i] : 0;
    sh[t] = v;
    __syncthreads();
#pragma unroll
    for (int d = 1; d < 256; d <<= 1) {
        int u = (t >= d) ? sh[t - d] : 0;
        __syncthreads();
        sh[t] += u;
        __syncthreads();
    }
    if (i < N) offs[i] = sh[t] - v;
    if (t == 255) bsum[blockIdx.x] = sh[255];
}

// Each block recomputes its exclusive prefix over bsum (NB<=256 values) -> no scanB launch.
__global__ __launch_bounds__(256) void scanC_kernel(int* __restrict__ offs, const int* __restrict__ bsum,
                                                    int N, int NB)
{
    __shared__ int sh[256];
    int t = threadIdx.x;
    int bid = blockIdx.x;
    int s = 0;
    for (int j = t; j < bid; j += 256) s += bsum[j];
    sh[t] = s;
    __syncthreads();
#pragma unroll
    for (int d = 128; d >= 1; d >>= 1) {
        if (t < d) sh[t] += sh[t + d];
        __syncthreads();
    }
    int base = sh[0];
    int i = bid * 256 + t;
    if (i < N) offs[i] += base;
    if (bid == NB - 1 && t == 0) offs[N] = base + bsum[NB - 1];
}

// ---------------- atomic-free scatter: srcs[offs[d]+rank[i]] = src[i] (pure stream) ----------
__global__ __launch_bounds__(256) void scatter_kernel(const int* __restrict__ src, const int* __restrict__ dst,
                                                      const int* __restrict__ rank, const int* __restrict__ offs,
                                                      int* __restrict__ srcs, int E)
{
    int i = blockIdx.x * 1024 + threadIdx.x;
#pragma unroll
    for (int it = 0; it < 4; ++it, i += 256) {
        if (i < E) srcs[offs[dst[i]] + rank[i]] = src[i];
    }
}

// ---------------- layer-0 aggregation (float4 16-lane gather, no LDS -> max occupancy) -------
// h = relu(segsum(m)/clip(deg,1) + [deg>0]*cl + (r_raw + crb))
__global__ __launch_bounds__(256) void agg_kernel(
    const float* __restrict__ m, const float* __restrict__ r,
    const int* __restrict__ off, const int* __restrict__ srcs,
    const float* __restrict__ cl, const float* __restrict__ crb,
    float* __restrict__ hout, int N)
{
    const int tid = threadIdx.x;
    const int lane = tid & 63;
    const int wave = tid >> 6;
    const int grp = lane >> 4;
    const int l16 = lane & 15;
    const int node0 = blockIdx.x * 64;

    int offv = off[min(node0 + lane, N)];
    int offend = off[min(node0 + 64, N)];
    float4 cl4 = *(const float4*)(cl + l16 * 4);
    float4 cb4 = *(const float4*)(crb + l16 * 4);

    int e0p = __shfl(offv, wave);
    int e1p = (wave < 63) ? __shfl(offv, wave + 1) : offend;
    int sv = (e0p + lane < e1p) ? srcs[e0p + lane] : 0;

    for (int idx = 0; idx < 16; ++idx) {
        int nn = wave + idx * 4;
        int node = node0 + nn;
        int e0 = __shfl(offv, nn);
        int e1 = (nn < 63) ? __shfl(offv, nn + 1) : offend;
        int cur_sv = sv;
        if (idx < 15) {
            int nx = nn + 4;
            int ne0 = __shfl(offv, nx);
            int ne1 = (nx < 63) ? __shfl(offv, nx + 1) : offend;
            sv = (ne0 + lane < ne1) ? srcs[ne0 + lane] : 0;
        }
        float4 r4 = make_float4(0.f, 0.f, 0.f, 0.f);
        if (node < N) r4 = *((const float4*)(r + (size_t)node * 64) + l16);

        float4 acc4[4];
#pragma unroll
        for (int t = 0; t < 4; ++t) acc4[t] = make_float4(0.f, 0.f, 0.f, 0.f);

        for (int base = e0; base < e1; base += 64) {
            int cnt = min(e1 - base, 64);
            int svs = (base == e0) ? cur_sv : ((base + lane < e1) ? srcs[base + lane] : 0);
            for (int u = 0; u < cnt; u += 16) {
#pragma unroll
                for (int t = 0; t < 4; ++t) {
                    int ei = u + t * 4 + grp;
                    int s = __shfl(svs, ei);
                    if (ei < cnt) {
                        float4 v = *((const float4*)(m + (size_t)s * 64) + l16);
                        acc4[t].x += v.x; acc4[t].y += v.y;
                        acc4[t].z += v.z; acc4[t].w += v.w;
                    }
                }
            }
        }
        float4 tot;
        tot.x = (acc4[0].x + acc4[1].x) + (acc4[2].x + acc4[3].x);
        tot.y = (acc4[0].y + acc4[1].y) + (acc4[2].y + acc4[3].y);
        tot.z = (acc4[0].z + acc4[1].z) + (acc4[2].z + acc4[3].z);
        tot.w = (acc4[0].w + acc4[1].w) + (acc4[2].w + acc4[3].w);
        tot.x += __shfl_xor(tot.x, 16); tot.x += __shfl_xor(tot.x, 32);
        tot.y += __shfl_xor(tot.y, 16); tot.y += __shfl_xor(tot.y, 32);
        tot.z += __shfl_xor(tot.z, 16); tot.z += __shfl_xor(tot.z, 32);
        tot.w += __shfl_xor(tot.w, 16); tot.w += __shfl_xor(tot.w, 32);

        int deg = e1 - e0;
        float inv = 1.f / (float)(deg > 0 ? deg : 1);
        if (lane < 16 && node < N) {
            float cadd = (deg > 0) ? 1.f : 0.f;
            float4 o;
            o.x = fmaxf(fmaf(tot.x, inv, fmaf(cadd, cl4.x, r4.x + cb4.x)), 0.f);
            o.y = fmaxf(fmaf(tot.y, inv, fmaf(cadd, cl4.y, r4.y + cb4.y)), 0.f);
            o.z = fmaxf(fmaf(tot.z, inv, fmaf(cadd, cl4.z, r4.z + cb4.z)), 0.f);
            o.w = fmaxf(fmaf(tot.w, inv, fmaf(cadd, cl4.w, r4.w + cb4.w)), 0.f);
            *(float4*)(hout + (size_t)node * 64 + l16 * 4) = o;
        }
    }
}

// ---------------- fused SAGE layer (layers 1-2): round-4 verbatim (52 VGPR, 26.1 KB, 72us) ---
// Gather is L2/LLC random-row BW-bound at ~4.5 TB/s (r7 falsified concurrency theory);
// this config saturates it. Do not touch occupancy or Bs chunking (r5/r6/r7 regressions).
template <bool SCORER>
__global__ __launch_bounds__(256) void sage_fused_kernel(
    const float* __restrict__ h,
    const int* __restrict__ off, const int* __restrict__ srcs,
    const float* __restrict__ Wl, const float* __restrict__ Wr, const float* __restrict__ bias,
    const float* __restrict__ sw1, const float* __restrict__ sb1,
    const float* __restrict__ sw2, const float* __restrict__ sb2,
    float* __restrict__ hout, float* __restrict__ sbuf, unsigned* __restrict__ red, int N)
{
    __shared__ float As[32][132];   // 16.9 KB
    __shared__ float Bs[32][64];    // 8 KB
    __shared__ float smax_sh[256];  // 1 KB

    const int tid = threadIdx.x;
    const int lane = tid & 63;
    const int wave = tid >> 6;
    const int grp = lane >> 4;
    const int l16 = lane & 15;
    const int node0 = blockIdx.x * 32;

    int offv = off[min(node0 + lane, N)];   // lanes 0..32 used

    int e0p = __shfl(offv, wave);
    int e1p = __shfl(offv, wave + 1);
    int sv = (e0p + lane < e1p) ? srcs[e0p + lane] : 0;

    for (int idx = 0; idx < 8; ++idx) {
        int nn = wave + idx * 4;
        int node = node0 + nn;
        int e0 = __shfl(offv, nn);
        int e1 = __shfl(offv, nn + 1);
        int cur_sv = sv;
        if (idx < 7) {
            int nx = nn + 4;
            int ne0 = __shfl(offv, nx);
            int ne1 = __shfl(offv, nx + 1);
            sv = (ne0 + lane < ne1) ? srcs[ne0 + lane] : 0;
        }
        float4 hv = make_float4(0.f, 0.f, 0.f, 0.f);
        if (node < N) hv = *((const float4*)(h + (size_t)node * 64) + l16);

        float4 acc4[4];
#pragma unroll
        for (int t = 0; t < 4; ++t) acc4[t] = make_float4(0.f, 0.f, 0.f, 0.f);

        for (int base = e0; base < e1; base += 64) {
            int cnt = min(e1 - base, 64);
            int svs = (base == e0) ? cur_sv : ((base + lane < e1) ? srcs[base + lane] : 0);
            for (int u = 0; u < cnt; u += 16) {
#pragma unroll
                for (int t = 0; t < 4; ++t) {
                    int ei = u + t * 4 + grp;
                    int s = __shfl(svs, ei);
                    if (ei < cnt) {
                        float4 v = *((const float4*)(h + (size_t)s * 64) + l16);
                        acc4[t].x += v.x; acc4[t].y += v.y;
                        acc4[t].z += v.z; acc4[t].w += v.w;
                    }
                }
            }
        }
        float4 tot;
        tot.x = (acc4[0].x + acc4[1].x) + (acc4[2].x + acc4[3].x);
        tot.y = (acc4[0].y + acc4[1].y) + (acc4[2].y + acc4[3].y);
        tot.z = (acc4[0].z + acc4[1].z) + (acc4[2].z + acc4[3].z);
        tot.w = (acc4[0].w + acc4[1].w) + (acc4[2].w + acc4[3].w);
        tot.x += __shfl_xor(tot.x, 16); tot.x += __shfl_xor(tot.x, 32);
        tot.y += __shfl_xor(tot.y, 16); tot.y += __shfl_xor(tot.y, 32);
        tot.z += __shfl_xor(tot.z, 16); tot.z += __shfl_xor(tot.z, 32);
        tot.w += __shfl_xor(tot.w, 16); tot.w += __shfl_xor(tot.w, 32);

        int deg = e1 - e0;
        float inv = 1.f / (float)(deg > 0 ? deg : 1);
        if (lane < 16) {
            float4 g4 = make_float4(tot.x * inv, tot.y * inv, tot.z * inv, tot.w * inv);
            *(float4*)&As[nn][l16 * 4] = g4;
            *(float4*)&As[nn][64 + l16 * 4] = hv;
        }
    }

    // ---- Phase 2: [32x128] @ [128x64], thread tile 2 rows x 4 cols
    const int cg = tid & 15;
    const int rg = tid >> 4;
    float acc[2][4];
#pragma unroll
    for (int i = 0; i < 2; ++i)
#pragma unroll
        for (int j = 0; j < 4; ++j) acc[i][j] = 0.f;

    for (int kc = 0; kc < 128; kc += 32) {
#pragma unroll
        for (int i = 0; i < 2; ++i) {
            int vi = i * 256 + tid;
            int k = vi >> 4;
            int c = (vi & 15) << 2;
            int kg = kc + k;
            const float* wp = (kg < 64) ? (Wl + (size_t)kg * 64 + c)
                                        : (Wr + (size_t)(kg - 64) * 64 + c);
            *(float4*)&Bs[k][c] = *(const float4*)wp;
        }
        __syncthreads();
#pragma unroll
        for (int k4 = 0; k4 < 32; k4 += 4) {
            float4 a4[2];
#pragma unroll
            for (int i = 0; i < 2; ++i)
                a4[i] = *(const float4*)&As[rg * 2 + i][kc + k4];   // broadcast
#pragma unroll
            for (int j = 0; j < 4; ++j) {
                float4 bv = *(const float4*)&Bs[k4 + j][cg * 4];
#pragma unroll
                for (int i = 0; i < 2; ++i) {
                    float av = ((const float*)&a4[i])[j];
                    acc[i][0] = fmaf(av, bv.x, acc[i][0]);
                    acc[i][1] = fmaf(av, bv.y, acc[i][1]);
                    acc[i][2] = fmaf(av, bv.z, acc[i][2]);
                    acc[i][3] = fmaf(av, bv.w, acc[i][3]);
                }
            }
        }
        __syncthreads();
    }

    float4 b4 = *(const float4*)(bias + cg * 4);

    if (!SCORER) {
#pragma unroll
        for (int i = 0; i < 2; ++i) {
            int row = node0 + rg * 2 + i;
            if (row < N) {
                float4 o;
                o.x = fmaxf(acc[i][0] + b4.x, 0.f);
                o.y = fmaxf(acc[i][1] + b4.y, 0.f);
                o.z = fmaxf(acc[i][2] + b4.z, 0.f);
                o.w = fmaxf(acc[i][3] + b4.w, 0.f);
                *(float4*)(hout + (size_t)row * 64 + cg * 4) = o;
            }
        }
        return;
    }

    // ---- SCORER: h2 -> As cols 0..63, then s = relu(h2@w1+b1)@w2 + b2 (h2 never hits HBM)
#pragma unroll
    for (int i = 0; i < 2; ++i) {
        float4 t;
        t.x = fmaxf(acc[i][0] + b4.x, 0.f);
        t.y = fmaxf(acc[i][1] + b4.y, 0.f);
        t.z = fmaxf(acc[i][2] + b4.z, 0.f);
        t.w = fmaxf(acc[i][3] + b4.w, 0.f);
        *(float4*)&As[rg * 2 + i][cg * 4] = t;
    }
    __syncthreads();

    float acc2[2][4];
#pragma unroll
    for (int i = 0; i < 2; ++i)
#pragma unroll
        for (int j = 0; j < 4; ++j) acc2[i][j] = 0.f;

    for (int kc = 0; kc < 64; kc += 32) {
#pragma unroll
        for (int i = 0; i < 2; ++i) {
            int vi = i * 256 + tid;
            int k = vi >> 4;
            int c = (vi & 15) << 2;
            *(float4*)&Bs[k][c] = *(const float4*)(sw1 + (size_t)(kc + k) * 64 + c);
        }
        __syncthreads();
#pragma unroll
        for (int k4 = 0; k4 < 32; k4 += 4) {
            float4 a4[2];
#pragma unroll
            for (int i = 0; i < 2; ++i)
                a4[i] = *(const float4*)&As[rg * 2 + i][kc + k4];
#pragma unroll
            for (int j = 0; j < 4; ++j) {
                float4 bv = *(const float4*)&Bs[k4 + j][cg * 4];
#pragma unroll
                for (int i = 0; i < 2; ++i) {
                    float av = ((const float*)&a4[i])[j];
                    acc2[i][0] = fmaf(av, bv.x, acc2[i][0]);
                    acc2[i][1] = fmaf(av, bv.y, acc2[i][1]);
                    acc2[i][2] = fmaf(av, bv.z, acc2[i][2]);
                    acc2[i][3] = fmaf(av, bv.w, acc2[i][3]);
                }
            }
        }
        __syncthreads();
    }

    float4 s1b = *(const float4*)(sb1 + cg * 4);
    float4 w24 = *(const float4*)(sw2 + cg * 4);
    float bb = sb2[0];
    float svals[2];
#pragma unroll
    for (int i = 0; i < 2; ++i) {
        float p = fmaxf(acc2[i][0] + s1b.x, 0.f) * w24.x;
        p = fmaf(fmaxf(acc2[i][1] + s1b.y, 0.f), w24.y, p);
        p = fmaf(fmaxf(acc2[i][2] + s1b.z, 0.f), w24.z, p);
        p = fmaf(fmaxf(acc2[i][3] + s1b.w, 0.f), w24.w, p);
#pragma unroll
        for (int d = 1; d <= 8; d <<= 1) p += __shfl_xor(p, d, 64);
        svals[i] = p;
    }
    float smx = -FLT_MAX;
    if (cg == 0) {
#pragma unroll
        for (int i = 0; i < 2; ++i) {
            int row = node0 + rg * 2 + i;
            if (row < N) {
                float s = svals[i] + bb;
                sbuf[row] = s;
                smx = fmaxf(smx, s);
            }
        }
    }
    smax_sh[tid] = smx;
    __syncthreads();
    for (int d = 128; d >= 1; d >>= 1) {
        if (tid < d) smax_sh[tid] = fmaxf(smax_sh[tid], smax_sh[tid + d]);
        __syncthreads();
    }
    if (tid == 0) atomicMax(red, enc_f(smax_sh[0]));
}

// ---------------- softmax: sum + finalize in ONE kernel (ticket spin, 128 resident blocks) ----
__global__ __launch_bounds__(256) void sumfinal_kernel(const float* __restrict__ s, const float* __restrict__ pos,
                                                       unsigned* __restrict__ red, float* __restrict__ out, int N)
{
    float mx = dec_f(red[0]);
    float se = 0.f, px = 0.f, py = 0.f;
    for (int i = blockIdx.x * blockDim.x + threadIdx.x; i < N; i += gridDim.x * blockDim.x) {
        float e = expf(s[i] - mx);
        se += e;
        px = fmaf(e, pos[2 * i], px);
        py = fmaf(e, pos[2 * i + 1], py);
    }
#pragma unroll
    for (int d = 32; d >= 1; d >>= 1) {
        se += __shfl_xor(se, d, 64);
        px += __shfl_xor(px, d, 64);
        py += __shfl_xor(py, d, 64);
    }
    if ((threadIdx.x & 63) == 0) {
        atomicAdd((float*)red + 1, se);
        atomicAdd((float*)red + 2, px);
        atomicAdd((float*)red + 3, py);
    }
    __threadfence();
    if (threadIdx.x == 0) {
        __hip_atomic_fetch_add(&red[4], 1u, __ATOMIC_ACQ_REL, __HIP_MEMORY_SCOPE_AGENT);
        while (__hip_atomic_load(&red[4], __ATOMIC_ACQUIRE, __HIP_MEMORY_SCOPE_AGENT) < (unsigned)gridDim.x) {}
    }
    __syncthreads();
    float S  = __uint_as_float(__hip_atomic_load(&red[1], __ATOMIC_RELAXED, __HIP_MEMORY_SCOPE_AGENT));
    float PX = __uint_as_float(__hip_atomic_load(&red[2], __ATOMIC_RELAXED, __HIP_MEMORY_SCOPE_AGENT));
    float PY = __uint_as_float(__hip_atomic_load(&red[3], __ATOMIC_RELAXED, __HIP_MEMORY_SCOPE_AGENT));
    float invS = 1.f / S;
    for (int i = blockIdx.x * blockDim.x + threadIdx.x; i < N; i += gridDim.x * blockDim.x)
        out[2 + i] = expf(s[i] - mx) * invS;
    if (blockIdx.x == 0 && threadIdx.x == 0) {
        out[0] = PX * invS;
        out[1] = PY * invS;
    }
}

extern "C" void kernel_launch(void* const* d_in, const int* in_sizes, int n_in,
                              void* d_out, int out_size, void* d_ws, size_t ws_size,
                              hipStream_t stream)
{
    const float* x    = (const float*)d_in[0];
    const float* pos  = (const float*)d_in[1];
    const int*   ei   = (const int*)d_in[2];
    const int*   qids = (const int*)d_in[3];
    const float* qrs  = (const float*)d_in[4];
    const float* emb  = (const float*)d_in[5];
    const float* ew   = (const float*)d_in[6];
    const float* eb   = (const float*)d_in[7];
    const float* Wl0  = (const float*)d_in[8];
    const float* Wr0  = (const float*)d_in[9];
    const float* b0   = (const float*)d_in[10];
    const float* Wl1  = (const float*)d_in[11];
    const float* Wr1  = (const float*)d_in[12];
    const float* b1   = (const float*)d_in[13];
    const float* Wl2  = (const float*)d_in[14];
    const float* Wr2  = (const float*)d_in[15];
    const float* b2   = (const float*)d_in[16];
    const float* sw1  = (const float*)d_in[17];
    const float* sb1  = (const float*)d_in[18];
    const float* sw2  = (const float*)d_in[19];
    const float* sb2  = (const float*)d_in[20];

    const int N  = in_sizes[0] / 128;
    const int E  = in_sizes[2] / 2;
    const int NQ = in_sizes[3];
    const int NB = (N + 255) / 256;

    char* base = (char*)d_ws;
    size_t wsoff = 0;
    auto take = [&](size_t bytes) -> char* {
        char* p = base + wsoff;
        wsoff = (wsoff + bytes + 255) & ~(size_t)255;
        return p;
    };
    int*      deg    = (int*)take((size_t)N * 4);
    int*      offs   = (int*)take((size_t)(N + 1) * 4);
    int*      rank   = (int*)take((size_t)E * 4);
    int*      bsum   = (int*)take((size_t)NB * 4);
    int*      srcs   = (int*)take((size_t)E * 4);
    float*    zout   = (float*)take(192 * 4);   // zq[64], cl[64], crb[64]
    unsigned* red    = (unsigned*)take(32);     // [0]=max [1]=sumexp [2]=px [3]=py [4]=ticket
    float*    mbuf   = (float*)take((size_t)N * 64 * 4);
    float*    rbuf   = (float*)take((size_t)N * 64 * 4);
    float*    hbuf   = (float*)take((size_t)N * 64 * 4);
    float*    sbuf   = (float*)take((size_t)N * 4);
    (void)ws_size; (void)n_in; (void)out_size;

    const int* esrc = ei;
    const int* edst = ei + E;

    hipMemsetAsync(deg, 0, (size_t)N * 4, stream);

    int schunks = (E + 4095) / 4096;
    int nCount = schunks * 8;
    int g64 = (N + 63) / 64;
    int g32 = (N + 31) / 32;

    // launch 1: gemm0 (independent) + count+rank (atomic-bound) + encoder, overlapped
    fused0_kernel<<<g64 + nCount + 1, 256, 0, stream>>>(edst, deg, rank, E, N,
                                                        x, Wl0, Wr0, mbuf, rbuf, g64, nCount,
                                                        qids, qrs, emb, ew, eb, b0, zout, NQ);
    scanA_kernel<<<NB, 256, 0, stream>>>(deg, offs, bsum, red, N);
    scanC_kernel<<<NB, 256, 0, stream>>>(offs, bsum, N, NB);
    // atomic-free scatter (pure stream)
    scatter_kernel<<<(E + 1023) / 1024, 256, 0, stream>>>(esrc, edst, rank, offs, srcs, E);
    // layer 0 aggregation (adds crb + cl here; gemm0 wrote raw products)
    agg_kernel<<<g64, 256, 0, stream>>>(mbuf, rbuf, offs, srcs, zout + 64, zout + 128, hbuf, N);
    // layer 1: fused agg-first + gemm (hbuf -> mbuf)
    sage_fused_kernel<false><<<g32, 256, 0, stream>>>(hbuf, offs, srcs, Wl1, Wr1, b1,
                                                      nullptr, nullptr, nullptr, nullptr,
                                                      mbuf, nullptr, nullptr, N);
    // layer 2 + scorer fused (mbuf -> sbuf, red[0])
    sage_fused_kernel<true><<<g32, 256, 0, stream>>>(mbuf, offs, srcs, Wl2, Wr2, b2,
                                                     sw1, sb1, sw2, sb2,
                                                     nullptr, sbuf, red, N);
    // softmax sum + finalize (single launch, internal grid sync)
    sumfinal_kernel<<<128, 256, 0, stream>>>(sbuf, pos, red, (float*)d_out, N);
}